// Round 2
// baseline (169.051 us; speedup 1.0000x reference)
//
#include <hip/hip_runtime.h>

typedef __attribute__((ext_vector_type(4))) float f32x4;
typedef __attribute__((ext_vector_type(8))) short bf16x8;

constexpr int Bsz = 4096, Asz = 32, Isz = 256, Osz = 256;
constexpr int BM = 64;                  // batch rows per block
constexpr int NKT = 8;                  // K-steps of 32
constexpr int NBLK = Asz * (Bsz / BM);  // 2048 blocks

// packed f32x2 -> bf16x2 (RNE), v_cvt_pk_bf16_f32 (no builtin on gfx950)
__device__ inline unsigned cvtpk(float lo, float hi) {
    unsigned r;
    asm("v_cvt_pk_bf16_f32 %0, %1, %2" : "=v"(r) : "v"(lo), "v"(hi));
    return r;
}

__device__ inline bf16x8 pack_frag(f32x4 a, f32x4 b) {
    union { bf16x8 v; unsigned u[4]; } r;
    r.u[0] = cvtpk(a[0], a[1]);
    r.u[1] = cvtpk(a[2], a[3]);
    r.u[2] = cvtpk(b[0], b[1]);
    r.u[3] = cvtpk(b[2], b[3]);
    return r.v;
}

__global__ __launch_bounds__(256, 4) void al_gemm(const float* __restrict__ x,
                                                  const float* __restrict__ w,
                                                  const float* __restrict__ bias,
                                                  float* __restrict__ out)
{
    // XCD-contiguous bijective swizzle (2048 % 8 == 0): XCD k owns logical
    // ids [k*256, (k+1)*256) = 4 full a-groups -> w working set 1 MB/XCD in L2.
    const int p  = blockIdx.x;
    const int l  = (p & 7) * (NBLK / 8) + (p >> 3);
    const int a  = l >> 6;               // assignment
    const int b0 = (l & 63) * BM;        // batch-row base

    const int t    = threadIdx.x;
    const int wid  = t >> 6;             // wave = N-quadrant
    const int lane = t & 63;
    const int llo  = lane & 15, lhi = lane >> 4;
    const int nb   = wid * 64;

    // Per-lane fragment base pointers (16x16x32 layout: row/col = lane&15,
    // k-slice = (lane>>4)*8). kt indexes via compile-time imm offsets.
    const float* ax[4];
    const float* bw[4];
#pragma unroll
    for (int m = 0; m < 4; ++m)
        ax[m] = x + ((size_t)(b0 + m * 16 + llo) * Asz + a) * Isz + lhi * 8;
#pragma unroll
    for (int n = 0; n < 4; ++n)
        bw[n] = w + ((size_t)a * Osz + nb + n * 16 + llo) * Isz + lhi * 8;

    // Fold bias into acc init: all 4 regs of a C-fragment share col = nb+n*16+llo.
    f32x4 acc[4][4];
#pragma unroll
    for (int n = 0; n < 4; ++n) {
        const float bv = bias[a * Osz + nb + n * 16 + llo];
#pragma unroll
        for (int m = 0; m < 4; ++m) acc[m][n] = (f32x4)(bv);
    }

#pragma unroll
    for (int kt = 0; kt < NKT; ++kt) {
        bf16x8 aF[4], bF[4];
#pragma unroll
        for (int m = 0; m < 4; ++m) {
            f32x4 lo = *(const f32x4*)(ax[m] + kt * 32);
            f32x4 hi = *(const f32x4*)(ax[m] + kt * 32 + 4);
            aF[m] = pack_frag(lo, hi);
        }
#pragma unroll
        for (int n = 0; n < 4; ++n) {
            f32x4 lo = *(const f32x4*)(bw[n] + kt * 32);
            f32x4 hi = *(const f32x4*)(bw[n] + kt * 32 + 4);
            bF[n] = pack_frag(lo, hi);
        }
#pragma unroll
        for (int m = 0; m < 4; ++m)
#pragma unroll
            for (int n = 0; n < 4; ++n)
                acc[m][n] = __builtin_amdgcn_mfma_f32_16x16x32_bf16(aF[m], bF[n], acc[m][n], 0, 0, 0);
    }

    // Epilogue: D[row = m*16 + lhi*4 + r][col = nb + n*16 + llo] (verified layout)
#pragma unroll
    for (int n = 0; n < 4; ++n) {
        const int col = nb + n * 16 + llo;
#pragma unroll
        for (int m = 0; m < 4; ++m) {
            const int row = b0 + m * 16 + lhi * 4;
            float* op = out + ((size_t)row * Asz + a) * Osz + col;
#pragma unroll
            for (int r = 0; r < 4; ++r)
                op[(size_t)r * Asz * Osz] = acc[m][n][r];
        }
    }
}

extern "C" void kernel_launch(void* const* d_in, const int* in_sizes, int n_in,
                              void* d_out, int out_size, void* d_ws, size_t ws_size,
                              hipStream_t stream) {
    const float* x    = (const float*)d_in[0];
    const float* w    = (const float*)d_in[1];
    const float* bias = (const float*)d_in[2];
    float* out        = (float*)d_out;
    al_gemm<<<dim3(NBLK), dim3(256), 0, stream>>>(x, w, bias, out);
}

// Round 3
// 113.809 us; speedup vs baseline: 1.4854x; 1.4854x over previous
//
#include <hip/hip_runtime.h>

typedef __attribute__((ext_vector_type(4))) float f32x4;
typedef __attribute__((ext_vector_type(8))) short bf16x8;

constexpr int Bsz = 4096, Asz = 32, Isz = 256, Osz = 256;
constexpr int BM = 64, NKT = 8;
constexpr int NBLK = Asz * (Bsz / BM);   // 2048

// packed f32x2 -> bf16x2 (RNE); no builtin on gfx950
__device__ inline unsigned cvtpk(float lo, float hi) {
    unsigned r;
    asm("v_cvt_pk_bf16_f32 %0, %1, %2" : "=v"(r) : "v"(lo), "v"(hi));
    return r;
}

// ---------------------------------------------------------------------------
// Pre-pack w [A,O,I] f32 -> bf16 fragment-linear: wf[((a*8+kt)*16+nf)*64+lane]
// holds the 8 bf16 (16 B) that lane `lane` of fragment (a,kt,nf) consumes.
// o = nf*16 + (lane&15), i = kt*32 + (lane>>4)*8 .. +8   (matches MFMA B-frag)
// ---------------------------------------------------------------------------
__global__ __launch_bounds__(256) void pack_w(const float* __restrict__ w,
                                              unsigned short* __restrict__ wf) {
    const int gid  = blockIdx.x * 256 + threadIdx.x;
    const int lane = gid & 63, nf = (gid >> 6) & 15, kt = (gid >> 10) & 7, a = gid >> 13;
    const int o  = nf * 16 + (lane & 15);
    const int i0 = kt * 32 + (lane >> 4) * 8;
    const float* s = w + (size_t)(a * Osz + o) * Isz + i0;
    f32x4 lo = *(const f32x4*)s, hi = *(const f32x4*)(s + 4);
    union { bf16x8 v; unsigned u[4]; } r;
    r.u[0] = cvtpk(lo[0], lo[1]); r.u[1] = cvtpk(lo[2], lo[3]);
    r.u[2] = cvtpk(hi[0], hi[1]); r.u[3] = cvtpk(hi[2], hi[3]);
    *(bf16x8*)(wf + (size_t)gid * 8) = r.v;
}

// ---------------------------------------------------------------------------
// Main GEMM: block = (a, 64 batch rows), 4 waves split O. No LDS, no barriers.
// Register-level 1-deep prefetch pipeline; 256-VGPR cap for headroom.
// ---------------------------------------------------------------------------
__global__ __launch_bounds__(256, 2) void al_gemm(const float* __restrict__ x,
                                                  const unsigned short* __restrict__ wf,
                                                  const float* __restrict__ bias,
                                                  float* __restrict__ out)
{
    // XCD-contiguous bijective swizzle (2048 % 8 == 0)
    const int p  = blockIdx.x;
    const int l  = (p & 7) * (NBLK / 8) + (p >> 3);
    const int a  = l >> 6;
    const int b0 = (l & 63) * BM;

    const int t    = threadIdx.x;
    const int wid  = t >> 6;
    const int lane = t & 63;
    const int llo  = lane & 15, lhi = lane >> 4;
    const int nb   = wid * 64;

    // A fragment base pointers (kt indexed via imm offsets: kt*128B <= 912 ok)
    const float* ax[4];
#pragma unroll
    for (int m = 0; m < 4; ++m)
        ax[m] = x + ((size_t)(b0 + m * 16 + llo) * Asz + a) * Isz + lhi * 8;

    // B: fragment-linear bf16, wave reads 4 contiguous-1KB frags per kt
    const unsigned short* bp = wf + ((size_t)((a * 8) * 16 + wid * 4) * 64 + lane) * 8;
    // per-kt stride: 16 frags * 64 lanes * 8 shorts = 8192 shorts (16 KB)
    // per-n  stride: 512 shorts (1 KB) -> imm offsets

    // bias folded into acc init (all 4 regs of a C-frag share col nb+n*16+llo)
    f32x4 acc[4][4];
#pragma unroll
    for (int n = 0; n < 4; ++n) {
        const float bv = bias[a * Osz + nb + n * 16 + llo];
#pragma unroll
        for (int m = 0; m < 4; ++m) acc[m][n] = (f32x4)(bv);
    }

    f32x4 aLo[4], aHi[4];   // prefetched A (f32)
    bf16x8 bN[4];           // prefetched B (bf16)

#pragma unroll
    for (int m = 0; m < 4; ++m) { aLo[m] = *(const f32x4*)(ax[m]); aHi[m] = *(const f32x4*)(ax[m] + 4); }
#pragma unroll
    for (int n = 0; n < 4; ++n) bN[n] = *(const bf16x8*)(bp + n * 512);

#pragma unroll
    for (int kt = 0; kt < NKT; ++kt) {
        // consume prefetched regs (compiler inserts the vmcnt wait here)
        bf16x8 aC[4], bC[4];
#pragma unroll
        for (int m = 0; m < 4; ++m) {
            union { bf16x8 v; unsigned u[4]; } r;
            r.u[0] = cvtpk(aLo[m][0], aLo[m][1]); r.u[1] = cvtpk(aLo[m][2], aLo[m][3]);
            r.u[2] = cvtpk(aHi[m][0], aHi[m][1]); r.u[3] = cvtpk(aHi[m][2], aHi[m][3]);
            aC[m] = r.v;
        }
#pragma unroll
        for (int n = 0; n < 4; ++n) bC[n] = bN[n];

        // issue next K-step's loads BEFORE the MFMAs (latency hides under them)
        if (kt < NKT - 1) {
#pragma unroll
            for (int m = 0; m < 4; ++m) {
                aLo[m] = *(const f32x4*)(ax[m] + (kt + 1) * 32);
                aHi[m] = *(const f32x4*)(ax[m] + (kt + 1) * 32 + 4);
            }
            const unsigned short* q = bp + (size_t)(kt + 1) * 8192;
#pragma unroll
            for (int n = 0; n < 4; ++n) bN[n] = *(const bf16x8*)(q + n * 512);
        }

#pragma unroll
        for (int m = 0; m < 4; ++m)
#pragma unroll
            for (int n = 0; n < 4; ++n)
                acc[m][n] = __builtin_amdgcn_mfma_f32_16x16x32_bf16(aC[m], bC[n], acc[m][n], 0, 0, 0);
    }

    // Epilogue: D[row = m*16 + lhi*4 + r][col = nb + n*16 + llo]
#pragma unroll
    for (int n = 0; n < 4; ++n) {
        const int col = nb + n * 16 + llo;
#pragma unroll
        for (int m = 0; m < 4; ++m) {
            const int row = b0 + m * 16 + lhi * 4;
            float* op = out + ((size_t)row * Asz + a) * Osz + col;
#pragma unroll
            for (int r = 0; r < 4; ++r)
                op[(size_t)r * Asz * Osz] = acc[m][n][r];
        }
    }
}

extern "C" void kernel_launch(void* const* d_in, const int* in_sizes, int n_in,
                              void* d_out, int out_size, void* d_ws, size_t ws_size,
                              hipStream_t stream) {
    const float* x    = (const float*)d_in[0];
    const float* w    = (const float*)d_in[1];
    const float* bias = (const float*)d_in[2];
    float* out        = (float*)d_out;
    unsigned short* wf = (unsigned short*)d_ws;   // 4 MB needed

    pack_w<<<dim3(Asz * NKT * 16 * 64 / 256), dim3(256), 0, stream>>>(w, wf);
    al_gemm<<<dim3(NBLK), dim3(256), 0, stream>>>(x, wf, bias, out);
}

// Round 4
// 79.273 us; speedup vs baseline: 2.1325x; 1.4357x over previous
//
#include <hip/hip_runtime.h>

typedef __attribute__((ext_vector_type(4))) float f32x4;
typedef __attribute__((ext_vector_type(8))) short bf16x8;

constexpr int Bsz = 4096, Asz = 32, Isz = 256, Osz = 256;
constexpr int BM = 64, NKT = 8;
constexpr int NBLK = Asz * (Bsz / BM);   // 2048

// packed f32x2 -> bf16x2 (RNE); no builtin on gfx950
__device__ inline unsigned cvtpk(float lo, float hi) {
    unsigned r;
    asm("v_cvt_pk_bf16_f32 %0, %1, %2" : "=v"(r) : "v"(lo), "v"(hi));
    return r;
}

// async global->LDS DMA, 16B per lane; dest = uniform base + lane*16 (linear!)
__device__ inline void gl_lds16(const void* g, void* l) {
    __builtin_amdgcn_global_load_lds((const __attribute__((address_space(1))) void*)g,
                                     (__attribute__((address_space(3))) void*)l, 16, 0, 0);
}

// ---------------------------------------------------------------------------
// Pre-pack w [A,O,I] f32 -> bf16 fragment-linear: wf[((a*8+kt)*16+nf)*64+lane]
// = 8 bf16 consumed by lane `lane` of B-fragment (a,kt,nf).
// o = nf*16 + (lane&15), i = kt*32 + (lane>>4)*8 .. +8
// ---------------------------------------------------------------------------
__global__ __launch_bounds__(256) void pack_w(const float* __restrict__ w,
                                              unsigned short* __restrict__ wf) {
    const int gid  = blockIdx.x * 256 + threadIdx.x;
    const int lane = gid & 63, nf = (gid >> 6) & 15, kt = (gid >> 10) & 7, a = gid >> 13;
    const int o  = nf * 16 + (lane & 15);
    const int i0 = kt * 32 + (lane >> 4) * 8;
    const float* s = w + (size_t)(a * Osz + o) * Isz + i0;
    f32x4 lo = *(const f32x4*)s, hi = *(const f32x4*)(s + 4);
    union { bf16x8 v; unsigned u[4]; } r;
    r.u[0] = cvtpk(lo[0], lo[1]); r.u[1] = cvtpk(lo[2], lo[3]);
    r.u[2] = cvtpk(hi[0], hi[1]); r.u[3] = cvtpk(hi[2], hi[3]);
    *(bf16x8*)(wf + (size_t)gid * 8) = r.v;
}

// ---------------------------------------------------------------------------
// Main GEMM, m97 structure: global_load_lds double-buffered staging,
// one barrier per K-step. Block = (a, 64 batch rows); 4 waves split O=256.
// A staged as f32 with XOR chunk swizzle (source-side), B staged bf16 linear.
// ---------------------------------------------------------------------------
__global__ __launch_bounds__(256) void al_gemm(const float* __restrict__ x,
                                               const unsigned short* __restrict__ wf,
                                               const float* __restrict__ bias,
                                               float* __restrict__ out)
{
    __shared__ char sA[2][8192];    // 64 rows x 32 f32, chunk-swizzled
    __shared__ char sB[2][16384];   // 16 frags x 64 lanes x 16B, linear

    // XCD-contiguous bijective swizzle (2048 % 8 == 0)
    const int p  = blockIdx.x;
    const int l  = (p & 7) * (NBLK / 8) + (p >> 3);
    const int a  = l >> 6;
    const int b0 = (l & 63) * BM;

    const int t    = threadIdx.x;
    const int wid  = t >> 6;
    const int lane = t & 63;
    const int llo  = lane & 15, lhi = lane >> 4;
    const int nb   = wid * 64;

    // --- staging source pointers (per-lane; LDS dests stay linear) ---
    // A: physical chunk pc = wid*128 + j*64 + lane; row = pc>>3, q = (pc&7)^(row&7)
    const float* asrc[2];
#pragma unroll
    for (int j = 0; j < 2; ++j) {
        const int pc  = wid * 128 + j * 64 + lane;
        const int row = pc >> 3;
        const int q   = (pc & 7) ^ (row & 7);
        asrc[j] = x + ((size_t)(b0 + row) * Asz + a) * Isz + q * 4;
    }
    // B: chunk c = (wid*4+j)*64 + lane, identical order in wf and LDS
    const unsigned short* bsrc[4];
#pragma unroll
    for (int j = 0; j < 4; ++j)
        bsrc[j] = wf + (size_t)a * (Osz * Isz) + (size_t)((wid * 4 + j) * 64 + lane) * 8;

    auto STAGE = [&](int buf, int kt) {
#pragma unroll
        for (int j = 0; j < 2; ++j)
            gl_lds16(asrc[j] + kt * 32, &sA[buf][wid * 2048 + j * 1024]);
#pragma unroll
        for (int j = 0; j < 4; ++j)
            gl_lds16(bsrc[j] + kt * 8192, &sB[buf][(wid * 4 + j) * 1024]);
    };

    // --- compute-side LDS addresses ---
    // logical A chunk (row=m*16+llo, q=2*lhi) at phys row*128 + (q^(llo&7))*16
    const int q0     = (2 * lhi) ^ (llo & 7);
    const int abase0 = llo * 128 + q0 * 16;
    const int abase1 = llo * 128 + (q0 ^ 1) * 16;
    const int bbase  = wid * 4096 + lane * 16;

    // bias folded into acc init (all 4 regs of a C-frag share col nb+n*16+llo)
    f32x4 acc[4][4];
#pragma unroll
    for (int n = 0; n < 4; ++n) {
        const float bv = bias[a * Osz + nb + n * 16 + llo];
#pragma unroll
        for (int m = 0; m < 4; ++m) acc[m][n] = (f32x4)(bv);
    }

    auto COMPUTE = [&](int buf) {
        bf16x8 aF[4], bF[4];
#pragma unroll
        for (int m = 0; m < 4; ++m) {
            f32x4 lo = *(const f32x4*)&sA[buf][abase0 + m * 2048];
            f32x4 hi = *(const f32x4*)&sA[buf][abase1 + m * 2048];
            union { bf16x8 v; unsigned u[4]; } r;
            r.u[0] = cvtpk(lo[0], lo[1]); r.u[1] = cvtpk(lo[2], lo[3]);
            r.u[2] = cvtpk(hi[0], hi[1]); r.u[3] = cvtpk(hi[2], hi[3]);
            aF[m] = r.v;
        }
#pragma unroll
        for (int n = 0; n < 4; ++n)
            bF[n] = *(const bf16x8*)&sB[buf][bbase + n * 1024];
#pragma unroll
        for (int m = 0; m < 4; ++m)
#pragma unroll
            for (int n = 0; n < 4; ++n)
                acc[m][n] = __builtin_amdgcn_mfma_f32_16x16x32_bf16(aF[m], bF[n], acc[m][n], 0, 0, 0);
    };

    STAGE(0, 0);
    __syncthreads();

    int cur = 0;
#pragma unroll
    for (int kt = 0; kt < NKT; ++kt) {
        if (kt < NKT - 1) STAGE(cur ^ 1, kt + 1);  // fire-and-forget DMA
        COMPUTE(cur);
        __syncthreads();                            // drains vmcnt; other blocks overlap
        cur ^= 1;
    }

    // Epilogue: D[row = m*16 + lhi*4 + r][col = nb + n*16 + llo]
#pragma unroll
    for (int n = 0; n < 4; ++n) {
        const int col = nb + n * 16 + llo;
#pragma unroll
        for (int m = 0; m < 4; ++m) {
            const int row = b0 + m * 16 + lhi * 4;
            float* op = out + ((size_t)row * Asz + a) * Osz + col;
#pragma unroll
            for (int r = 0; r < 4; ++r)
                op[(size_t)r * Asz * Osz] = acc[m][n][r];
        }
    }
}

extern "C" void kernel_launch(void* const* d_in, const int* in_sizes, int n_in,
                              void* d_out, int out_size, void* d_ws, size_t ws_size,
                              hipStream_t stream) {
    const float* x    = (const float*)d_in[0];
    const float* w    = (const float*)d_in[1];
    const float* bias = (const float*)d_in[2];
    float* out        = (float*)d_out;
    unsigned short* wf = (unsigned short*)d_ws;   // 4 MB

    pack_w<<<dim3(Asz * NKT * 16 * 64 / 256), dim3(256), 0, stream>>>(w, wf);
    al_gemm<<<dim3(NBLK), dim3(256), 0, stream>>>(x, wf, bias, out);
}